// Round 12
// baseline (1359.308 us; speedup 1.0000x reference)
//
#include <hip/hip_runtime.h>
#include <cstdint>
#include <cstddef>

#define B_  2048
#define T_  32
#define V_  32000
#define H_  1024
#define A_  1000
#define H3  3072

typedef short short8 __attribute__((ext_vector_type(8)));
typedef float f32x4  __attribute__((ext_vector_type(4)));

typedef __attribute__((address_space(1))) void* as1v;
typedef __attribute__((address_space(3))) void* as3v;

__device__ __forceinline__ unsigned short f2bf(float f) {
  union { float f; unsigned u; } v; v.f = f;
  unsigned r = v.u + 0x7FFFu + ((v.u >> 16) & 1u);   // RNE
  return (unsigned short)(r >> 16);
}
__device__ __forceinline__ float bf2f(unsigned short s) {
  union { unsigned u; float f; } v; v.u = ((unsigned)s) << 16;
  return v.f;
}
__device__ __forceinline__ float sigmoidf(float x) {
  return 1.f / (1.f + __expf(-x));
}

// Journal:
// T2 swizzle (R3, verified): LDS row r, 16B-block c holds global block
//   c^(r&7); SQ_LDS_BANK_CONFLICT 7.37e7 -> 0, total 1829 -> 1453.
// R4 (falsified): dbuf under __syncthreads() neutral (vmcnt(0) drain).
// R5 (verified, -81 us): T4 counted-vmcnt dbuf in step_fused.
// R6 (falsified): FULL col-split -> +12 us/step (4x scattered gather).
// R7 (falsified): by-fastest gemm_ew grid: FETCH 300 -> 804 MB. bx-fastest.
// R8 (verified, -39 us): step 4 blocks/CU (32-col slices, 40 KB LDS).
// R9 (falsified): 2x2 wave split neutral-worse -> step NOT LDS-read-bound.
// R10 (verified, -24 us): T4 dbuf on gemm_ew (286 -> 256 us).
// R11 (falsified): nontemporal EW stores -> WRITE 192 -> 378 MB (L2 was
//   write-combining the strided u16 stores; nt bypasses the merge -> 2x
//   write amplification + colder EW for the step gather). Plain stores
//   restored. RULE: no cache-policy experiments without counter mechanism.
//   gemm_final T4 (co-deployed, proven transform) kept.

// ---------------------------------------------------------------- converts
__global__ void conv_bf16(const float* __restrict__ src, unsigned short* __restrict__ dst, int n4) {
  int i = blockIdx.x * blockDim.x + threadIdx.x;
  if (i >= n4) return;
  float4 v = ((const float4*)src)[i];
  ushort4 o;
  o.x = f2bf(v.x); o.y = f2bf(v.y); o.z = f2bf(v.z); o.w = f2bf(v.w);
  ((ushort4*)dst)[i] = o;
}

// h1_w [1000,1024] -> padded bf16 [1024,1024] (rows >= 1000 zero)
__global__ void conv_h1w(const float* __restrict__ src, unsigned short* __restrict__ dst) {
  int i = blockIdx.x * blockDim.x + threadIdx.x;
  if (i >= 1024 * 1024) return;
  int row = i >> 10;
  dst[i] = (row < A_) ? f2bf(src[i]) : (unsigned short)0;
}

__global__ void init_state(float* __restrict__ state, unsigned short* __restrict__ hbf0) {
  int i = blockIdx.x * blockDim.x + threadIdx.x;
  if (i < B_ * H_) { state[i] = 0.f; hbf0[i] = 0; }
}

// alive bitmask per row + utterance transpose
__global__ void prep(const int* __restrict__ utt, unsigned* __restrict__ alivemask,
                     int* __restrict__ uttT) {
  int b = blockIdx.x * blockDim.x + threadIdx.x;
  if (b >= B_) return;
  unsigned mask = 0, alive = 1;
  #pragma unroll
  for (int t = 0; t < T_; t++) {
    int tk = utt[b * T_ + t];
    mask |= alive << t;
    if (tk == 0) alive = 0;
    uttT[t * B_ + b] = tk;
  }
  alivemask[b] = mask;
}

// ---------------------------------------------------------------- EW = bf16(emb @ w_ih^T + b_ih)
// [32000, 3072] bf16. 128x128 tile; grid (24, 250) bx-fastest (R7 lesson).
// T2 swizzle + T4 counted-vmcnt dbuf (R10). Plain u16 stores (R11 lesson:
// L2 write-combines them to full lines; nt store doubles HBM writes).
__global__ void __launch_bounds__(256) gemm_ew(
    const unsigned short* __restrict__ Abase,   // emb_bf [32000][1024]
    const unsigned short* __restrict__ W,       // wih_bf [3072][1024]
    const float* __restrict__ bias,             // b_ih [3072]
    unsigned short* __restrict__ Cw)            // EW [32000][3072]
{
  __shared__ __align__(16) unsigned short lA[2][128 * 64];   // 32 KB
  __shared__ __align__(16) unsigned short lB[2][128 * 64];   // 32 KB
  const int tid  = threadIdx.x;
  const int lane = tid & 63;
  const int wv   = tid >> 6;
  const int wr   = (wv >> 1) * 64;
  const int wc   = (wv & 1) * 64;
  const int lm   = lane & 15;
  const int lq   = lane >> 4;
  const int bx   = blockIdx.x, by = blockIdx.y;

  f32x4 acc[4][4];
  #pragma unroll
  for (int i = 0; i < 4; i++)
    #pragma unroll
    for (int j = 0; j < 4; j++)
      acc[i][j] = (f32x4){0.f, 0.f, 0.f, 0.f};

  // 8 global_load_lds per thread per STAGE — the vmcnt unit below.
  auto STAGE = [&](int buf, int kt) {
    #pragma unroll
    for (int r = 0; r < 4; r++) {
      int li  = r * 256 + tid;
      int row = li >> 3;
      int gc  = (li & 7) ^ (row & 7);          // pre-swizzled source block
      const unsigned short* ga = Abase + (size_t)(by * 128 + row) * H_ + kt + gc * 8;
      __builtin_amdgcn_global_load_lds((as1v)ga, (as3v)(&lA[buf][(size_t)li * 8]), 16, 0, 0);
      const unsigned short* gb = W + (size_t)(bx * 128 + row) * H_ + kt + gc * 8;
      __builtin_amdgcn_global_load_lds((as1v)gb, (as3v)(&lB[buf][(size_t)li * 8]), 16, 0, 0);
    }
  };

  STAGE(0, 0);

  // T4 K-loop: prefetch stays in flight across barriers; vmcnt never drains
  // to 0 mid-loop (R5/R10-verified structure).
  #pragma unroll 1
  for (int kti = 0; kti < 16; kti++) {
    const int cur = kti & 1;
    __builtin_amdgcn_s_barrier();                    // B1: all done reading cur^1
    __builtin_amdgcn_sched_barrier(0);
    if (kti < 15) {
      STAGE(cur ^ 1, (kti + 1) * 64);
      asm volatile("s_waitcnt vmcnt(8)" ::: "memory");   // cur's 8 retired
    } else {
      asm volatile("s_waitcnt vmcnt(0)" ::: "memory");   // final tile
    }
    __builtin_amdgcn_sched_barrier(0);
    __builtin_amdgcn_s_barrier();                    // B2: cur ready for all
    __builtin_amdgcn_sched_barrier(0);
    #pragma unroll
    for (int kk = 0; kk < 2; kk++) {
      const int cs = (((kk << 2) | lq) ^ (lm & 7)) << 3;   // swizzled read col
      short8 af[4], bf[4];
      #pragma unroll
      for (int i = 0; i < 4; i++)
        af[i] = *(const short8*)&lA[cur][(wr + i * 16 + lm) * 64 + cs];
      #pragma unroll
      for (int j = 0; j < 4; j++)
        bf[j] = *(const short8*)&lB[cur][(wc + j * 16 + lm) * 64 + cs];
      #pragma unroll
      for (int i = 0; i < 4; i++)
        #pragma unroll
        for (int j = 0; j < 4; j++)
          acc[i][j] = __builtin_amdgcn_mfma_f32_16x16x32_bf16(af[i], bf[j], acc[i][j], 0, 0, 0);
    }
  }
  // epilogue: bias + bf16 store (scalar u16; L2 write-back merges to full
  // lines — verified R11: bypassing L2 doubles HBM writes)
  #pragma unroll
  for (int i = 0; i < 4; i++) {
    int row0 = by * 128 + wr + i * 16 + lq * 4;
    #pragma unroll
    for (int j = 0; j < 4; j++) {
      int col = bx * 128 + wc + j * 16 + lm;
      float bv = bias[col];
      #pragma unroll
      for (int rg = 0; rg < 4; rg++)
        Cw[(size_t)(row0 + rg) * H3 + col] = f2bf(acc[i][j][rg] + bv);
    }
  }
}

// ---------------------------------------------------------------- final logits GEMM
// T4 counted-vmcnt dbuf (R11, proven transform).
__global__ void __launch_bounds__(256) gemm_final(
    const unsigned short* __restrict__ Abase,   // h bf16 [2048][1024]
    const unsigned short* __restrict__ W,       // h1w_bf [1024][1024]
    float* __restrict__ C)                      // logits [2048][1024]
{
  __shared__ __align__(16) unsigned short lA[2][128 * 64];
  __shared__ __align__(16) unsigned short lB[2][128 * 64];
  const int tid  = threadIdx.x;
  const int lane = tid & 63;
  const int wv   = tid >> 6;
  const int wr   = (wv >> 1) * 64;
  const int wc   = (wv & 1) * 64;
  const int lm   = lane & 15;
  const int lq   = lane >> 4;
  const int bx   = blockIdx.x, by = blockIdx.y;

  f32x4 acc[4][4];
  #pragma unroll
  for (int i = 0; i < 4; i++)
    #pragma unroll
    for (int j = 0; j < 4; j++)
      acc[i][j] = (f32x4){0.f, 0.f, 0.f, 0.f};

  auto STAGE = [&](int buf, int kt) {
    #pragma unroll
    for (int r = 0; r < 4; r++) {
      int li  = r * 256 + tid;
      int row = li >> 3;
      int gc  = (li & 7) ^ (row & 7);
      const unsigned short* ga = Abase + (size_t)(by * 128 + row) * H_ + kt + gc * 8;
      __builtin_amdgcn_global_load_lds((as1v)ga, (as3v)(&lA[buf][(size_t)li * 8]), 16, 0, 0);
      const unsigned short* gb = W + (size_t)(bx * 128 + row) * H_ + kt + gc * 8;
      __builtin_amdgcn_global_load_lds((as1v)gb, (as3v)(&lB[buf][(size_t)li * 8]), 16, 0, 0);
    }
  };

  STAGE(0, 0);

  #pragma unroll 1
  for (int kti = 0; kti < 16; kti++) {
    const int cur = kti & 1;
    __builtin_amdgcn_s_barrier();                    // B1
    __builtin_amdgcn_sched_barrier(0);
    if (kti < 15) {
      STAGE(cur ^ 1, (kti + 1) * 64);
      asm volatile("s_waitcnt vmcnt(8)" ::: "memory");
    } else {
      asm volatile("s_waitcnt vmcnt(0)" ::: "memory");
    }
    __builtin_amdgcn_sched_barrier(0);
    __builtin_amdgcn_s_barrier();                    // B2
    __builtin_amdgcn_sched_barrier(0);
    #pragma unroll
    for (int kk = 0; kk < 2; kk++) {
      const int cs = (((kk << 2) | lq) ^ (lm & 7)) << 3;
      short8 af[4], bf[4];
      #pragma unroll
      for (int i = 0; i < 4; i++)
        af[i] = *(const short8*)&lA[cur][(wr + i * 16 + lm) * 64 + cs];
      #pragma unroll
      for (int j = 0; j < 4; j++)
        bf[j] = *(const short8*)&lB[cur][(wc + j * 16 + lm) * 64 + cs];
      #pragma unroll
      for (int i = 0; i < 4; i++)
        #pragma unroll
        for (int j = 0; j < 4; j++)
          acc[i][j] = __builtin_amdgcn_mfma_f32_16x16x32_bf16(af[i], bf[j], acc[i][j], 0, 0, 0);
    }
  }
  #pragma unroll
  for (int i = 0; i < 4; i++) {
    int row0 = by * 128 + wr + i * 16 + lq * 4;
    #pragma unroll
    for (int j = 0; j < 4; j++) {
      int col = bx * 128 + wc + j * 16 + lm;
      #pragma unroll
      for (int rg = 0; rg < 4; rg++)
        C[(size_t)(row0 + rg) * 1024 + col] = acc[i][j][rg];
    }
  }
}

// ---------------------------------------------------------------- fused GH GEMM + GRU update
// Block (hx, bb): batch rows [bb*64,+64), h-cols [hx*32,+32), all 3 gates.
// R8 form (verified best): row-split waves, 32-col slices, 40 KB LDS,
// 4 blocks/CU, T2 swizzle, T4 counted-vmcnt dbuf with vmcnt(5).
__global__ void __launch_bounds__(256, 4) step_fused(
    const unsigned short* __restrict__ EW,             // [V,3H] bf16
    const int* __restrict__ uttT, int t,               // token ids, step
    const unsigned short* __restrict__ hin,            // h_{t-1} bf16 [B,H]
    const unsigned short* __restrict__ whh_bf,         // [3H,H] bf16
    const float* __restrict__ bhh,
    float* __restrict__ state,                         // f32 h (in/out)
    unsigned short* __restrict__ hout,                 // h_t bf16 [B,H]
    const unsigned* __restrict__ amask)
{
  __shared__ __align__(16) unsigned short lA[2][64 * 64];       // 16 KB
  __shared__ __align__(16) unsigned short lB[2][3 * 32 * 64];   // 24 KB

  const int tid  = threadIdx.x;
  const int lane = tid & 63;
  const int wv   = tid >> 6;        // 0..3 (row quarter)
  const int lm   = lane & 15;
  const int lq   = lane >> 4;
  const int hx   = blockIdx.x;      // 0..31 (32-col slice)
  const int bb   = blockIdx.y;      // 0..31

  // 5 global_load_lds per thread per STAGE — the vmcnt unit below.
  auto STAGE = [&](int buf, int kt) {
    // stage A (h rows): 64x64 bf16 = 2 x 256 x 16B, source block pre-swizzled
    #pragma unroll
    for (int it = 0; it < 2; it++) {
      int li  = it * 256 + tid;
      int row = li >> 3;                  // 0..63
      int gc  = (li & 7) ^ (row & 7);
      const unsigned short* ga = hin + (size_t)(bb * 64 + row) * H_ + kt + gc * 8;
      __builtin_amdgcn_global_load_lds((as1v)ga, (as3v)(&lA[buf][(size_t)li * 8]), 16, 0, 0);
    }
    // stage B (w_hh rows, 3 gates x 32 rows): 3 x 256 x 16B
    #pragma unroll
    for (int gg = 0; gg < 3; gg++) {
      int li  = gg * 256 + tid;
      int g   = li >> 8;                  // == gg
      int row = (li >> 3) & 31;           // 0..31
      int gc  = (li & 7) ^ (row & 7);
      const unsigned short* gb = whh_bf + (size_t)((g << 10) + hx * 32 + row) * H_ + kt + gc * 8;
      __builtin_amdgcn_global_load_lds((as1v)gb, (as3v)(&lB[buf][(size_t)li * 8]), 16, 0, 0);
    }
  };

  // issue first K-tile before the (long-latency) epilogue gather
  STAGE(0, 0);

  // ---- prefetch epilogue operands (latency hides under K-loop; these loads
  // also count in vmcnt — iter 0's vmcnt(5) over-waits them once, harmless)
  int tokr[4];
  #pragma unroll
  for (int rg = 0; rg < 4; rg++)
    tokr[rg] = uttT[t * B_ + bb * 64 + wv * 16 + lq * 4 + rg];

  float hreg[2][4];
  float gir[2][4], giz[2][4], gin[2][4];
  #pragma unroll
  for (int j = 0; j < 2; j++) {
    int col = hx * 32 + j * 16 + lm;
    #pragma unroll
    for (int rg = 0; rg < 4; rg++) {
      int row = bb * 64 + wv * 16 + lq * 4 + rg;
      hreg[j][rg] = state[(size_t)row * H_ + col];
      const unsigned short* ep = EW + (size_t)tokr[rg] * H3 + col;
      gir[j][rg] = bf2f(ep[0]);
      giz[j][rg] = bf2f(ep[H_]);
      gin[j][rg] = bf2f(ep[2 * H_]);
    }
  }

  f32x4 acc[3][2];
  #pragma unroll
  for (int g = 0; g < 3; g++)
    #pragma unroll
    for (int j = 0; j < 2; j++)
      acc[g][j] = (f32x4){0.f, 0.f, 0.f, 0.f};

  // T4 K-loop: prefetch stays in flight across barriers; vmcnt never drains
  // to 0 mid-loop.
  #pragma unroll 1
  for (int kti = 0; kti < 16; kti++) {
    const int cur = kti & 1;
    __builtin_amdgcn_s_barrier();                    // B1
    __builtin_amdgcn_sched_barrier(0);
    if (kti < 15) {
      STAGE(cur ^ 1, (kti + 1) * 64);
      asm volatile("s_waitcnt vmcnt(5)" ::: "memory");   // cur's 5 retired
    } else {
      asm volatile("s_waitcnt vmcnt(0)" ::: "memory");   // final tile
    }
    __builtin_amdgcn_sched_barrier(0);
    __builtin_amdgcn_s_barrier();                    // B2: cur ready for all
    __builtin_amdgcn_sched_barrier(0);
    #pragma unroll
    for (int kk = 0; kk < 2; kk++) {
      const int cs = (((kk << 2) | lq) ^ (lm & 7)) << 3;   // swizzled read col
      short8 af = *(const short8*)&lA[cur][(wv * 16 + lm) * 64 + cs];
      #pragma unroll
      for (int g = 0; g < 3; g++) {
        #pragma unroll
        for (int j = 0; j < 2; j++) {
          short8 bf = *(const short8*)&lB[cur][g * 2048 + (j * 16 + lm) * 64 + cs];
          acc[g][j] = __builtin_amdgcn_mfma_f32_16x16x32_bf16(af, bf, acc[g][j], 0, 0, 0);
        }
      }
    }
  }

  // ---- fused epilogue: bias + gates + GRU update + alive select
  #pragma unroll
  for (int j = 0; j < 2; j++) {
    int col = hx * 32 + j * 16 + lm;
    float bhr = bhh[col];
    float bhz = bhh[H_ + col];
    float bhn = bhh[2 * H_ + col];
    #pragma unroll
    for (int rg = 0; rg < 4; rg++) {
      int row = bb * 64 + wv * 16 + lq * 4 + rg;
      float r = sigmoidf(gir[j][rg] + acc[0][j][rg] + bhr);
      float z = sigmoidf(giz[j][rg] + acc[1][j][rg] + bhz);
      float n = tanhf(gin[j][rg] + r * (acc[2][j][rg] + bhn));
      float h = hreg[j][rg];
      float nh = (1.f - z) * n + z * h;
      float o = ((amask[row] >> t) & 1u) ? nh : h;
      size_t si = (size_t)row * H_ + col;
      state[si] = o;
      hout[si] = f2bf(o);
    }
  }
}

// ---------------------------------------------------------------- softmax head
__global__ void __launch_bounds__(256) softmax_k(const float* __restrict__ logits,
                                                 const float* __restrict__ h1b,
                                                 float* __restrict__ out)
{
  int b = blockIdx.x;
  int tid = threadIdx.x;
  __shared__ float red[8];
  float v[4];
  float lmax = -3.4e38f;
  #pragma unroll
  for (int k = 0; k < 4; k++) {
    int j = tid + k * 256;
    float x = (j < A_) ? (logits[(size_t)b * 1024 + j] + h1b[j]) : -3.4e38f;
    v[k] = x;
    lmax = fmaxf(lmax, x);
  }
  #pragma unroll
  for (int off = 1; off < 64; off <<= 1) lmax = fmaxf(lmax, __shfl_xor(lmax, off, 64));
  if ((tid & 63) == 0) red[tid >> 6] = lmax;
  __syncthreads();
  lmax = fmaxf(fmaxf(red[0], red[1]), fmaxf(red[2], red[3]));
  float s = 0.f;
  #pragma unroll
  for (int k = 0; k < 4; k++) {
    int j = tid + k * 256;
    float e = (j < A_) ? expf(v[k] - lmax) : 0.f;
    v[k] = e; s += e;
  }
  #pragma unroll
  for (int off = 1; off < 64; off <<= 1) s += __shfl_xor(s, off, 64);
  if ((tid & 63) == 0) red[4 + (tid >> 6)] = s;
  __syncthreads();
  s = red[4] + red[5] + red[6] + red[7];
  float inv = 1.f / s;
  #pragma unroll
  for (int k = 0; k < 4; k++) {
    int j = tid + k * 256;
    if (j < A_) out[(size_t)b * A_ + j] = v[k] * inv;
  }
}

// ---------------------------------------------------------------- launch
extern "C" void kernel_launch(void* const* d_in, const int* in_sizes, int n_in,
                              void* d_out, int out_size, void* d_ws, size_t ws_size,
                              hipStream_t stream)
{
  (void)in_sizes; (void)n_in; (void)out_size; (void)ws_size;
  const int*   utt   = (const int*)d_in[0];
  // d_in[1] global_idxes: unused by reference
  const float* emb_w = (const float*)d_in[2];
  const float* w_ih  = (const float*)d_in[3];
  const float* w_hh  = (const float*)d_in[4];
  const float* b_ih  = (const float*)d_in[5];
  const float* b_hh  = (const float*)d_in[6];
  const float* h1_w  = (const float*)d_in[7];
  const float* h1_b  = (const float*)d_in[8];
  float* out = (float*)d_out;

  char* ws = (char*)d_ws;
  size_t off = 0;
  auto alloc = [&](size_t bytes) {
    void* p = ws + off;
    off += (bytes + 255) & ~(size_t)255;
    return p;
  };
  // emb_bf region (65.5 MB) is dead after gemm_ew; overlay the small
  // per-iteration buffers inside it (written only after gemm_ew completes).
  unsigned short* emb_bf = (unsigned short*)alloc((size_t)V_ * H_ * 2);       // 65.5 MB
  unsigned short* wih_bf = (unsigned short*)alloc((size_t)H3 * H_ * 2);       // 6.3 MB
  unsigned short* EW     = (unsigned short*)alloc((size_t)V_ * H3 * 2);       // 196.6 MB
  unsigned short* whh_bf = (unsigned short*)alloc((size_t)H3 * H_ * 2);       // 6.3 MB
  int*            uttT   = (int*)alloc((size_t)B_ * T_ * 4);
  unsigned*       amask  = (unsigned*)alloc((size_t)B_ * 4);

  char* ov = (char*)emb_bf;           // overlay carve
  unsigned short* h1w_bf = (unsigned short*)(ov);                 // 2.1 MB
  float*          state  = (float*)(ov + 2097152);                // 8.4 MB
  unsigned short* hbf0   = (unsigned short*)(ov + 10485760);      // 4.2 MB
  unsigned short* hbf1   = (unsigned short*)(ov + 14680064);      // 4.2 MB
  float*          logits = (float*)(ov + 18874368);               // 8.4 MB  (ends 27.3 MB < 65.5)

  int n4 = V_ * H_ / 4;
  conv_bf16<<<(n4 + 255) / 256, 256, 0, stream>>>(emb_w, emb_bf, n4);
  n4 = H3 * H_ / 4;
  conv_bf16<<<(n4 + 255) / 256, 256, 0, stream>>>(w_ih, wih_bf, n4);
  conv_bf16<<<(n4 + 255) / 256, 256, 0, stream>>>(w_hh, whh_bf, n4);
  prep<<<(B_ + 255) / 256, 256, 0, stream>>>(utt, amask, uttT);

  dim3 gew(H3 / 128, V_ / 128);       // 24 x 250 — bx fastest (R7 lesson)
  gemm_ew<<<gew, 256, 0, stream>>>(emb_bf, wih_bf, b_ih, EW);

  // emb_bf dead from here; overlay region becomes live
  conv_h1w<<<(1024 * 1024) / 256, 256, 0, stream>>>(h1_w, h1w_bf);
  init_state<<<(B_ * H_) / 256, 256, 0, stream>>>(state, hbf0);

  unsigned short* hb[2] = { hbf0, hbf1 };
  dim3 gst(32, 32);                   // hx x bb  (1024 blocks, 4/CU)
  for (int t = 0; t < T_; t++) {
    step_fused<<<gst, 256, 0, stream>>>(EW, uttT, t, hb[t & 1], whh_bf, b_hh,
                                        state, hb[(t + 1) & 1], amask);
  }
  dim3 gf(1024 / 128, B_ / 128);      // 8 x 16
  gemm_final<<<gf, 256, 0, stream>>>(hb[0], h1w_bf, logits);
  softmax_k<<<B_, 256, 0, stream>>>(logits, h1_b, out);
}

// Round 13
// 1277.704 us; speedup vs baseline: 1.0639x; 1.0639x over previous
//
#include <hip/hip_runtime.h>
#include <cstdint>
#include <cstddef>

#define B_  2048
#define T_  32
#define V_  32000
#define H_  1024
#define A_  1000
#define H3  3072

typedef short short8 __attribute__((ext_vector_type(8)));
typedef float f32x4  __attribute__((ext_vector_type(4)));

typedef __attribute__((address_space(1))) void* as1v;
typedef __attribute__((address_space(3))) void* as3v;

__device__ __forceinline__ unsigned short f2bf(float f) {
  union { float f; unsigned u; } v; v.f = f;
  unsigned r = v.u + 0x7FFFu + ((v.u >> 16) & 1u);   // RNE
  return (unsigned short)(r >> 16);
}
__device__ __forceinline__ float bf2f(unsigned short s) {
  union { unsigned u; float f; } v; v.u = ((unsigned)s) << 16;
  return v.f;
}
__device__ __forceinline__ float sigmoidf(float x) {
  return 1.f / (1.f + __expf(-x));
}

// Journal:
// T2 swizzle (R3, verified): LDS bank conflicts 7.37e7 -> 0; 1829 -> 1453.
// R4 (falsified): dbuf under __syncthreads() neutral (vmcnt(0) drain).
// R5 (verified, -81 us): T4 counted-vmcnt dbuf in step_fused.
// R6 (falsified): FULL col-split -> +12 us/step (4x scattered gather).
// R7 (falsified): by-fastest gemm_ew grid: FETCH 300 -> 804 MB.
// R8 (verified, -39 us): step 4 blocks/CU (32-col slices, 40 KB LDS).
// R9 (falsified): 2x2 wave split neutral -> step NOT LDS-read-bound.
// R10 (verified, -24 us): T4 dbuf on gemm_ew.
// R11 (falsified): nontemporal EW stores -> 2x WRITE_SIZE. Reverted.
// R12: noise calibration — identical step code spans 1309-1372 across runs;
//   treat deltas < ~50 us as ambiguous.
// R13: T1 XCD swizzle on step grid. Round-robin dispatch scatters panel
//   sharers across XCDs -> hin re-read 32x (134 MB/step), whh 32x (201
//   MB/step) from L3. Group 4 hx-slices per XCD (decode below): whh 768 KB
//   stays L2-resident/XCD (201 -> 6.3 MB), hin once per XCD (134 -> 34 MB).
//   Pure bijective index remap; math bit-identical.

// ---------------------------------------------------------------- converts
__global__ void conv_bf16(const float* __restrict__ src, unsigned short* __restrict__ dst, int n4) {
  int i = blockIdx.x * blockDim.x + threadIdx.x;
  if (i >= n4) return;
  float4 v = ((const float4*)src)[i];
  ushort4 o;
  o.x = f2bf(v.x); o.y = f2bf(v.y); o.z = f2bf(v.z); o.w = f2bf(v.w);
  ((ushort4*)dst)[i] = o;
}

// h1_w [1000,1024] -> padded bf16 [1024,1024] (rows >= 1000 zero)
__global__ void conv_h1w(const float* __restrict__ src, unsigned short* __restrict__ dst) {
  int i = blockIdx.x * blockDim.x + threadIdx.x;
  if (i >= 1024 * 1024) return;
  int row = i >> 10;
  dst[i] = (row < A_) ? f2bf(src[i]) : (unsigned short)0;
}

__global__ void init_state(float* __restrict__ state, unsigned short* __restrict__ hbf0) {
  int i = blockIdx.x * blockDim.x + threadIdx.x;
  if (i < B_ * H_) { state[i] = 0.f; hbf0[i] = 0; }
}

// alive bitmask per row + utterance transpose
__global__ void prep(const int* __restrict__ utt, unsigned* __restrict__ alivemask,
                     int* __restrict__ uttT) {
  int b = blockIdx.x * blockDim.x + threadIdx.x;
  if (b >= B_) return;
  unsigned mask = 0, alive = 1;
  #pragma unroll
  for (int t = 0; t < T_; t++) {
    int tk = utt[b * T_ + t];
    mask |= alive << t;
    if (tk == 0) alive = 0;
    uttT[t * B_ + b] = tk;
  }
  alivemask[b] = mask;
}

// ---------------------------------------------------------------- EW = bf16(emb @ w_ih^T + b_ih)
// [32000, 3072] bf16. 128x128 tile; grid (24, 250) bx-fastest (R7 lesson).
// T2 swizzle + T4 counted-vmcnt dbuf (R10). Plain u16 stores (R11 lesson).
__global__ void __launch_bounds__(256) gemm_ew(
    const unsigned short* __restrict__ Abase,   // emb_bf [32000][1024]
    const unsigned short* __restrict__ W,       // wih_bf [3072][1024]
    const float* __restrict__ bias,             // b_ih [3072]
    unsigned short* __restrict__ Cw)            // EW [32000][3072]
{
  __shared__ __align__(16) unsigned short lA[2][128 * 64];   // 32 KB
  __shared__ __align__(16) unsigned short lB[2][128 * 64];   // 32 KB
  const int tid  = threadIdx.x;
  const int lane = tid & 63;
  const int wv   = tid >> 6;
  const int wr   = (wv >> 1) * 64;
  const int wc   = (wv & 1) * 64;
  const int lm   = lane & 15;
  const int lq   = lane >> 4;
  const int bx   = blockIdx.x, by = blockIdx.y;

  f32x4 acc[4][4];
  #pragma unroll
  for (int i = 0; i < 4; i++)
    #pragma unroll
    for (int j = 0; j < 4; j++)
      acc[i][j] = (f32x4){0.f, 0.f, 0.f, 0.f};

  // 8 global_load_lds per thread per STAGE — the vmcnt unit below.
  auto STAGE = [&](int buf, int kt) {
    #pragma unroll
    for (int r = 0; r < 4; r++) {
      int li  = r * 256 + tid;
      int row = li >> 3;
      int gc  = (li & 7) ^ (row & 7);          // pre-swizzled source block
      const unsigned short* ga = Abase + (size_t)(by * 128 + row) * H_ + kt + gc * 8;
      __builtin_amdgcn_global_load_lds((as1v)ga, (as3v)(&lA[buf][(size_t)li * 8]), 16, 0, 0);
      const unsigned short* gb = W + (size_t)(bx * 128 + row) * H_ + kt + gc * 8;
      __builtin_amdgcn_global_load_lds((as1v)gb, (as3v)(&lB[buf][(size_t)li * 8]), 16, 0, 0);
    }
  };

  STAGE(0, 0);

  // T4 K-loop: prefetch stays in flight across barriers; vmcnt never drains
  // to 0 mid-loop (R5/R10-verified structure).
  #pragma unroll 1
  for (int kti = 0; kti < 16; kti++) {
    const int cur = kti & 1;
    __builtin_amdgcn_s_barrier();                    // B1: all done reading cur^1
    __builtin_amdgcn_sched_barrier(0);
    if (kti < 15) {
      STAGE(cur ^ 1, (kti + 1) * 64);
      asm volatile("s_waitcnt vmcnt(8)" ::: "memory");   // cur's 8 retired
    } else {
      asm volatile("s_waitcnt vmcnt(0)" ::: "memory");   // final tile
    }
    __builtin_amdgcn_sched_barrier(0);
    __builtin_amdgcn_s_barrier();                    // B2: cur ready for all
    __builtin_amdgcn_sched_barrier(0);
    #pragma unroll
    for (int kk = 0; kk < 2; kk++) {
      const int cs = (((kk << 2) | lq) ^ (lm & 7)) << 3;   // swizzled read col
      short8 af[4], bf[4];
      #pragma unroll
      for (int i = 0; i < 4; i++)
        af[i] = *(const short8*)&lA[cur][(wr + i * 16 + lm) * 64 + cs];
      #pragma unroll
      for (int j = 0; j < 4; j++)
        bf[j] = *(const short8*)&lB[cur][(wc + j * 16 + lm) * 64 + cs];
      #pragma unroll
      for (int i = 0; i < 4; i++)
        #pragma unroll
        for (int j = 0; j < 4; j++)
          acc[i][j] = __builtin_amdgcn_mfma_f32_16x16x32_bf16(af[i], bf[j], acc[i][j], 0, 0, 0);
    }
  }
  // epilogue: bias + bf16 store (scalar u16; L2 write-back merges to full
  // lines — verified R11: bypassing L2 doubles HBM writes)
  #pragma unroll
  for (int i = 0; i < 4; i++) {
    int row0 = by * 128 + wr + i * 16 + lq * 4;
    #pragma unroll
    for (int j = 0; j < 4; j++) {
      int col = bx * 128 + wc + j * 16 + lm;
      float bv = bias[col];
      #pragma unroll
      for (int rg = 0; rg < 4; rg++)
        Cw[(size_t)(row0 + rg) * H3 + col] = f2bf(acc[i][j][rg] + bv);
    }
  }
}

// ---------------------------------------------------------------- final logits GEMM
// T4 counted-vmcnt dbuf (R11, proven transform).
__global__ void __launch_bounds__(256) gemm_final(
    const unsigned short* __restrict__ Abase,   // h bf16 [2048][1024]
    const unsigned short* __restrict__ W,       // h1w_bf [1024][1024]
    float* __restrict__ C)                      // logits [2048][1024]
{
  __shared__ __align__(16) unsigned short lA[2][128 * 64];
  __shared__ __align__(16) unsigned short lB[2][128 * 64];
  const int tid  = threadIdx.x;
  const int lane = tid & 63;
  const int wv   = tid >> 6;
  const int wr   = (wv >> 1) * 64;
  const int wc   = (wv & 1) * 64;
  const int lm   = lane & 15;
  const int lq   = lane >> 4;
  const int bx   = blockIdx.x, by = blockIdx.y;

  f32x4 acc[4][4];
  #pragma unroll
  for (int i = 0; i < 4; i++)
    #pragma unroll
    for (int j = 0; j < 4; j++)
      acc[i][j] = (f32x4){0.f, 0.f, 0.f, 0.f};

  auto STAGE = [&](int buf, int kt) {
    #pragma unroll
    for (int r = 0; r < 4; r++) {
      int li  = r * 256 + tid;
      int row = li >> 3;
      int gc  = (li & 7) ^ (row & 7);
      const unsigned short* ga = Abase + (size_t)(by * 128 + row) * H_ + kt + gc * 8;
      __builtin_amdgcn_global_load_lds((as1v)ga, (as3v)(&lA[buf][(size_t)li * 8]), 16, 0, 0);
      const unsigned short* gb = W + (size_t)(bx * 128 + row) * H_ + kt + gc * 8;
      __builtin_amdgcn_global_load_lds((as1v)gb, (as3v)(&lB[buf][(size_t)li * 8]), 16, 0, 0);
    }
  };

  STAGE(0, 0);

  #pragma unroll 1
  for (int kti = 0; kti < 16; kti++) {
    const int cur = kti & 1;
    __builtin_amdgcn_s_barrier();                    // B1
    __builtin_amdgcn_sched_barrier(0);
    if (kti < 15) {
      STAGE(cur ^ 1, (kti + 1) * 64);
      asm volatile("s_waitcnt vmcnt(8)" ::: "memory");
    } else {
      asm volatile("s_waitcnt vmcnt(0)" ::: "memory");
    }
    __builtin_amdgcn_sched_barrier(0);
    __builtin_amdgcn_s_barrier();                    // B2
    __builtin_amdgcn_sched_barrier(0);
    #pragma unroll
    for (int kk = 0; kk < 2; kk++) {
      const int cs = (((kk << 2) | lq) ^ (lm & 7)) << 3;
      short8 af[4], bf[4];
      #pragma unroll
      for (int i = 0; i < 4; i++)
        af[i] = *(const short8*)&lA[cur][(wr + i * 16 + lm) * 64 + cs];
      #pragma unroll
      for (int j = 0; j < 4; j++)
        bf[j] = *(const short8*)&lB[cur][(wc + j * 16 + lm) * 64 + cs];
      #pragma unroll
      for (int i = 0; i < 4; i++)
        #pragma unroll
        for (int j = 0; j < 4; j++)
          acc[i][j] = __builtin_amdgcn_mfma_f32_16x16x32_bf16(af[i], bf[j], acc[i][j], 0, 0, 0);
    }
  }
  #pragma unroll
  for (int i = 0; i < 4; i++) {
    int row0 = by * 128 + wr + i * 16 + lq * 4;
    #pragma unroll
    for (int j = 0; j < 4; j++) {
      int col = bx * 128 + wc + j * 16 + lm;
      #pragma unroll
      for (int rg = 0; rg < 4; rg++)
        C[(size_t)(row0 + rg) * 1024 + col] = acc[i][j][rg];
    }
  }
}

// ---------------------------------------------------------------- fused GH GEMM + GRU update
// R8 compute form + R13 XCD-aware block decode. 1-D grid of 1024; assuming
// round-robin dispatch (block n -> XCD n%8, m09/m157 heuristic), XCD x hosts
// hx in {4x..4x+3} for ALL bb: the 4 whh slices (768 KB) stay L2-resident
// per XCD, and each hin bb-panel is fetched once per XCD instead of once
// per block. Bijective remap; math bit-identical.
__global__ void __launch_bounds__(256, 4) step_fused(
    const unsigned short* __restrict__ EW,             // [V,3H] bf16
    const int* __restrict__ uttT, int t,               // token ids, step
    const unsigned short* __restrict__ hin,            // h_{t-1} bf16 [B,H]
    const unsigned short* __restrict__ whh_bf,         // [3H,H] bf16
    const float* __restrict__ bhh,
    float* __restrict__ state,                         // f32 h (in/out)
    unsigned short* __restrict__ hout,                 // h_t bf16 [B,H]
    const unsigned* __restrict__ amask)
{
  __shared__ __align__(16) unsigned short lA[2][64 * 64];       // 16 KB
  __shared__ __align__(16) unsigned short lB[2][3 * 32 * 64];   // 24 KB

  const int tid  = threadIdx.x;
  const int lane = tid & 63;
  const int wv   = tid >> 6;        // 0..3 (row quarter)
  const int lm   = lane & 15;
  const int lq   = lane >> 4;
  // R13 XCD-grouped decode: f = xcd + 8*(bb*4 + hx_low)
  const int f    = blockIdx.x;              // 0..1023
  const int hx   = (f & 7) * 4 + ((f >> 3) & 3);   // 0..31
  const int bb   = f >> 5;                          // 0..31

  // 5 global_load_lds per thread per STAGE — the vmcnt unit below.
  auto STAGE = [&](int buf, int kt) {
    // stage A (h rows): 64x64 bf16 = 2 x 256 x 16B, source block pre-swizzled
    #pragma unroll
    for (int it = 0; it < 2; it++) {
      int li  = it * 256 + tid;
      int row = li >> 3;                  // 0..63
      int gc  = (li & 7) ^ (row & 7);
      const unsigned short* ga = hin + (size_t)(bb * 64 + row) * H_ + kt + gc * 8;
      __builtin_amdgcn_global_load_lds((as1v)ga, (as3v)(&lA[buf][(size_t)li * 8]), 16, 0, 0);
    }
    // stage B (w_hh rows, 3 gates x 32 rows): 3 x 256 x 16B
    #pragma unroll
    for (int gg = 0; gg < 3; gg++) {
      int li  = gg * 256 + tid;
      int g   = li >> 8;                  // == gg
      int row = (li >> 3) & 31;           // 0..31
      int gc  = (li & 7) ^ (row & 7);
      const unsigned short* gb = whh_bf + (size_t)((g << 10) + hx * 32 + row) * H_ + kt + gc * 8;
      __builtin_amdgcn_global_load_lds((as1v)gb, (as3v)(&lB[buf][(size_t)li * 8]), 16, 0, 0);
    }
  };

  // issue first K-tile before the (long-latency) epilogue gather
  STAGE(0, 0);

  // ---- prefetch epilogue operands (latency hides under K-loop; these loads
  // also count in vmcnt — iter 0's vmcnt(5) over-waits them once, harmless)
  int tokr[4];
  #pragma unroll
  for (int rg = 0; rg < 4; rg++)
    tokr[rg] = uttT[t * B_ + bb * 64 + wv * 16 + lq * 4 + rg];

  float hreg[2][4];
  float gir[2][4], giz[2][4], gin[2][4];
  #pragma unroll
  for (int j = 0; j < 2; j++) {
    int col = hx * 32 + j * 16 + lm;
    #pragma unroll
    for (int rg = 0; rg < 4; rg++) {
      int row = bb * 64 + wv * 16 + lq * 4 + rg;
      hreg[j][rg] = state[(size_t)row * H_ + col];
      const unsigned short* ep = EW + (size_t)tokr[rg] * H3 + col;
      gir[j][rg] = bf2f(ep[0]);
      giz[j][rg] = bf2f(ep[H_]);
      gin[j][rg] = bf2f(ep[2 * H_]);
    }
  }

  f32x4 acc[3][2];
  #pragma unroll
  for (int g = 0; g < 3; g++)
    #pragma unroll
    for (int j = 0; j < 2; j++)
      acc[g][j] = (f32x4){0.f, 0.f, 0.f, 0.f};

  // T4 K-loop: prefetch stays in flight across barriers; vmcnt never drains
  // to 0 mid-loop.
  #pragma unroll 1
  for (int kti = 0; kti < 16; kti++) {
    const int cur = kti & 1;
    __builtin_amdgcn_s_barrier();                    // B1
    __builtin_amdgcn_sched_barrier(0);
    if (kti < 15) {
      STAGE(cur ^ 1, (kti + 1) * 64);
      asm volatile("s_waitcnt vmcnt(5)" ::: "memory");   // cur's 5 retired
    } else {
      asm volatile("s_waitcnt vmcnt(0)" ::: "memory");   // final tile
    }
    __builtin_amdgcn_sched_barrier(0);
    __builtin_amdgcn_s_barrier();                    // B2: cur ready for all
    __builtin_amdgcn_sched_barrier(0);
    #pragma unroll
    for (int kk = 0; kk < 2; kk++) {
      const int cs = (((kk << 2) | lq) ^ (lm & 7)) << 3;   // swizzled read col
      short8 af = *(const short8*)&lA[cur][(wv * 16 + lm) * 64 + cs];
      #pragma unroll
      for (int g = 0; g < 3; g++) {
        #pragma unroll
        for (int j = 0; j < 2; j++) {
          short8 bf = *(const short8*)&lB[cur][g * 2048 + (j * 16 + lm) * 64 + cs];
          acc[g][j] = __builtin_amdgcn_mfma_f32_16x16x32_bf16(af, bf, acc[g][j], 0, 0, 0);
        }
      }
    }
  }

  // ---- fused epilogue: bias + gates + GRU update + alive select
  #pragma unroll
  for (int j = 0; j < 2; j++) {
    int col = hx * 32 + j * 16 + lm;
    float bhr = bhh[col];
    float bhz = bhh[H_ + col];
    float bhn = bhh[2 * H_ + col];
    #pragma unroll
    for (int rg = 0; rg < 4; rg++) {
      int row = bb * 64 + wv * 16 + lq * 4 + rg;
      float r = sigmoidf(gir[j][rg] + acc[0][j][rg] + bhr);
      float z = sigmoidf(giz[j][rg] + acc[1][j][rg] + bhz);
      float n = tanhf(gin[j][rg] + r * (acc[2][j][rg] + bhn));
      float h = hreg[j][rg];
      float nh = (1.f - z) * n + z * h;
      float o = ((amask[row] >> t) & 1u) ? nh : h;
      size_t si = (size_t)row * H_ + col;
      state[si] = o;
      hout[si] = f2bf(o);
    }
  }
}

// ---------------------------------------------------------------- softmax head
__global__ void __launch_bounds__(256) softmax_k(const float* __restrict__ logits,
                                                 const float* __restrict__ h1b,
                                                 float* __restrict__ out)
{
  int b = blockIdx.x;
  int tid = threadIdx.x;
  __shared__ float red[8];
  float v[4];
  float lmax = -3.4e38f;
  #pragma unroll
  for (int k = 0; k < 4; k++) {
    int j = tid + k * 256;
    float x = (j < A_) ? (logits[(size_t)b * 1024 + j] + h1b[j]) : -3.4e38f;
    v[k] = x;
    lmax = fmaxf(lmax, x);
  }
  #pragma unroll
  for (int off = 1; off < 64; off <<= 1) lmax = fmaxf(lmax, __shfl_xor(lmax, off, 64));
  if ((tid & 63) == 0) red[tid >> 6] = lmax;
  __syncthreads();
  lmax = fmaxf(fmaxf(red[0], red[1]), fmaxf(red[2], red[3]));
  float s = 0.f;
  #pragma unroll
  for (int k = 0; k < 4; k++) {
    int j = tid + k * 256;
    float e = (j < A_) ? expf(v[k] - lmax) : 0.f;
    v[k] = e; s += e;
  }
  #pragma unroll
  for (int off = 1; off < 64; off <<= 1) s += __shfl_xor(s, off, 64);
  if ((tid & 63) == 0) red[4 + (tid >> 6)] = s;
  __syncthreads();
  s = red[4] + red[5] + red[6] + red[7];
  float inv = 1.f / s;
  #pragma unroll
  for (int k = 0; k < 4; k++) {
    int j = tid + k * 256;
    if (j < A_) out[(size_t)b * A_ + j] = v[k] * inv;
  }
}

// ---------------------------------------------------------------- launch
extern "C" void kernel_launch(void* const* d_in, const int* in_sizes, int n_in,
                              void* d_out, int out_size, void* d_ws, size_t ws_size,
                              hipStream_t stream)
{
  (void)in_sizes; (void)n_in; (void)out_size; (void)ws_size;
  const int*   utt   = (const int*)d_in[0];
  // d_in[1] global_idxes: unused by reference
  const float* emb_w = (const float*)d_in[2];
  const float* w_ih  = (const float*)d_in[3];
  const float* w_hh  = (const float*)d_in[4];
  const float* b_ih  = (const float*)d_in[5];
  const float* b_hh  = (const float*)d_in[6];
  const float* h1_w  = (const float*)d_in[7];
  const float* h1_b  = (const float*)d_in[8];
  float* out = (float*)d_out;

  char* ws = (char*)d_ws;
  size_t off = 0;
  auto alloc = [&](size_t bytes) {
    void* p = ws + off;
    off += (bytes + 255) & ~(size_t)255;
    return p;
  };
  // emb_bf region (65.5 MB) is dead after gemm_ew; overlay the small
  // per-iteration buffers inside it (written only after gemm_ew completes).
  unsigned short* emb_bf = (unsigned short*)alloc((size_t)V_ * H_ * 2);       // 65.5 MB
  unsigned short* wih_bf = (unsigned short*)alloc((size_t)H3 * H_ * 2);       // 6.3 MB
  unsigned short* EW     = (unsigned short*)alloc((size_t)V_ * H3 * 2);       // 196.6 MB
  unsigned short* whh_bf = (unsigned short*)alloc((size_t)H3 * H_ * 2);       // 6.3 MB
  int*            uttT   = (int*)alloc((size_t)B_ * T_ * 4);
  unsigned*       amask  = (unsigned*)alloc((size_t)B_ * 4);

  char* ov = (char*)emb_bf;           // overlay carve
  unsigned short* h1w_bf = (unsigned short*)(ov);                 // 2.1 MB
  float*          state  = (float*)(ov + 2097152);                // 8.4 MB
  unsigned short* hbf0   = (unsigned short*)(ov + 10485760);      // 4.2 MB
  unsigned short* hbf1   = (unsigned short*)(ov + 14680064);      // 4.2 MB
  float*          logits = (float*)(ov + 18874368);               // 8.4 MB  (ends 27.3 MB < 65.5)

  int n4 = V_ * H_ / 4;
  conv_bf16<<<(n4 + 255) / 256, 256, 0, stream>>>(emb_w, emb_bf, n4);
  n4 = H3 * H_ / 4;
  conv_bf16<<<(n4 + 255) / 256, 256, 0, stream>>>(w_ih, wih_bf, n4);
  conv_bf16<<<(n4 + 255) / 256, 256, 0, stream>>>(w_hh, whh_bf, n4);
  prep<<<(B_ + 255) / 256, 256, 0, stream>>>(utt, amask, uttT);

  dim3 gew(H3 / 128, V_ / 128);       // 24 x 250 — bx fastest (R7 lesson)
  gemm_ew<<<gew, 256, 0, stream>>>(emb_bf, wih_bf, b_ih, EW);

  // emb_bf dead from here; overlay region becomes live
  conv_h1w<<<(1024 * 1024) / 256, 256, 0, stream>>>(h1_w, h1w_bf);
  init_state<<<(B_ * H_) / 256, 256, 0, stream>>>(state, hbf0);

  unsigned short* hb[2] = { hbf0, hbf1 };
  for (int t = 0; t < T_; t++) {
    step_fused<<<1024, 256, 0, stream>>>(EW, uttT, t, hb[t & 1], whh_bf, b_hh,
                                         state, hb[(t + 1) & 1], amask);
  }
  dim3 gf(1024 / 128, B_ / 128);      // 8 x 16
  gemm_final<<<gf, 256, 0, stream>>>(hb[0], h1w_bf, logits);
  softmax_k<<<B_, 256, 0, stream>>>(logits, h1_b, out);
}

// Round 14
// 1240.327 us; speedup vs baseline: 1.0959x; 1.0301x over previous
//
#include <hip/hip_runtime.h>
#include <cstdint>
#include <cstddef>

#define B_  2048
#define T_  32
#define V_  32000
#define H_  1024
#define A_  1000
#define H3  3072

typedef short short8 __attribute__((ext_vector_type(8)));
typedef float f32x4  __attribute__((ext_vector_type(4)));

typedef __attribute__((address_space(1))) void* as1v;
typedef __attribute__((address_space(3))) void* as3v;

__device__ __forceinline__ unsigned short f2bf(float f) {
  union { float f; unsigned u; } v; v.f = f;
  unsigned r = v.u + 0x7FFFu + ((v.u >> 16) & 1u);   // RNE
  return (unsigned short)(r >> 16);
}
__device__ __forceinline__ float bf2f(unsigned short s) {
  union { unsigned u; float f; } v; v.u = ((unsigned)s) << 16;
  return v.f;
}
__device__ __forceinline__ float sigmoidf(float x) {
  return 1.f / (1.f + __expf(-x));
}

// Journal:
// T2 swizzle (R3, verified): LDS bank conflicts 7.37e7 -> 0; 1829 -> 1453.
// R4 (falsified): dbuf under __syncthreads() neutral (vmcnt(0) drain).
// R5 (verified, -81 us): T4 counted-vmcnt dbuf in step_fused.
// R6 (falsified): FULL col-split -> +12 us/step (4x scattered gather).
// R7 (falsified): by-fastest gemm_ew grid: FETCH 300 -> 804 MB.
// R8 (verified, -39 us): step 4 blocks/CU (32-col slices, 40 KB LDS).
// R9 (falsified): 2x2 wave split neutral -> step NOT LDS-read-bound.
// R10 (verified, -24 us): T4 dbuf on gemm_ew.
// R11 (falsified): nontemporal EW stores -> 2x WRITE_SIZE. Reverted.
// R12: noise calibration — deltas < ~50 us ambiguous.
// R13 (verified, -82 us vs R12): T1 XCD-grouped step decode (4 hx/XCD).
// R14: T1 on gemm_ew — A-panel sharers (24 bx-blocks) currently span all
//   8 XCDs -> panel fetched >=8x; FETCH 300 vs 72 ideal. Decode groups
//   3 bx-slices per XCD (W 768 KB L2-resident; A-panel once per XCD,
//   XCDs sweep by in lockstep for L3 reuse). Bijective; bit-identical.

// ---------------------------------------------------------------- converts
__global__ void conv_bf16(const float* __restrict__ src, unsigned short* __restrict__ dst, int n4) {
  int i = blockIdx.x * blockDim.x + threadIdx.x;
  if (i >= n4) return;
  float4 v = ((const float4*)src)[i];
  ushort4 o;
  o.x = f2bf(v.x); o.y = f2bf(v.y); o.z = f2bf(v.z); o.w = f2bf(v.w);
  ((ushort4*)dst)[i] = o;
}

// h1_w [1000,1024] -> padded bf16 [1024,1024] (rows >= 1000 zero)
__global__ void conv_h1w(const float* __restrict__ src, unsigned short* __restrict__ dst) {
  int i = blockIdx.x * blockDim.x + threadIdx.x;
  if (i >= 1024 * 1024) return;
  int row = i >> 10;
  dst[i] = (row < A_) ? f2bf(src[i]) : (unsigned short)0;
}

__global__ void init_state(float* __restrict__ state, unsigned short* __restrict__ hbf0) {
  int i = blockIdx.x * blockDim.x + threadIdx.x;
  if (i < B_ * H_) { state[i] = 0.f; hbf0[i] = 0; }
}

// alive bitmask per row + utterance transpose
__global__ void prep(const int* __restrict__ utt, unsigned* __restrict__ alivemask,
                     int* __restrict__ uttT) {
  int b = blockIdx.x * blockDim.x + threadIdx.x;
  if (b >= B_) return;
  unsigned mask = 0, alive = 1;
  #pragma unroll
  for (int t = 0; t < T_; t++) {
    int tk = utt[b * T_ + t];
    mask |= alive << t;
    if (tk == 0) alive = 0;
    uttT[t * B_ + b] = tk;
  }
  alivemask[b] = mask;
}

// ---------------------------------------------------------------- EW = bf16(emb @ w_ih^T + b_ih)
// [32000, 3072] bf16. 128x128 tile; 1-D grid 6000 with R14 XCD-grouped
// decode. T2 swizzle + T4 counted-vmcnt dbuf (R10). Plain u16 stores (R11).
__global__ void __launch_bounds__(256) gemm_ew(
    const unsigned short* __restrict__ Abase,   // emb_bf [32000][1024]
    const unsigned short* __restrict__ W,       // wih_bf [3072][1024]
    const float* __restrict__ bias,             // b_ih [3072]
    unsigned short* __restrict__ Cw)            // EW [32000][3072]
{
  __shared__ __align__(16) unsigned short lA[2][128 * 64];   // 32 KB
  __shared__ __align__(16) unsigned short lB[2][128 * 64];   // 32 KB
  const int tid  = threadIdx.x;
  const int lane = tid & 63;
  const int wv   = tid >> 6;
  const int wr   = (wv >> 1) * 64;
  const int wc   = (wv & 1) * 64;
  const int lm   = lane & 15;
  const int lq   = lane >> 4;
  // R14 XCD-grouped decode: f = xcd + 8*(by*3 + bxl); XCD x owns
  // bx in {3x..3x+2} for all by (W slices L2-resident, A-panel 1x/XCD).
  const int f    = blockIdx.x;          // 0..5999
  const int xcd  = f & 7;
  const int idx  = f >> 3;              // 0..749
  const int bx   = xcd * 3 + (idx % 3); // 0..23
  const int by   = idx / 3;             // 0..249

  f32x4 acc[4][4];
  #pragma unroll
  for (int i = 0; i < 4; i++)
    #pragma unroll
    for (int j = 0; j < 4; j++)
      acc[i][j] = (f32x4){0.f, 0.f, 0.f, 0.f};

  // 8 global_load_lds per thread per STAGE — the vmcnt unit below.
  auto STAGE = [&](int buf, int kt) {
    #pragma unroll
    for (int r = 0; r < 4; r++) {
      int li  = r * 256 + tid;
      int row = li >> 3;
      int gc  = (li & 7) ^ (row & 7);          // pre-swizzled source block
      const unsigned short* ga = Abase + (size_t)(by * 128 + row) * H_ + kt + gc * 8;
      __builtin_amdgcn_global_load_lds((as1v)ga, (as3v)(&lA[buf][(size_t)li * 8]), 16, 0, 0);
      const unsigned short* gb = W + (size_t)(bx * 128 + row) * H_ + kt + gc * 8;
      __builtin_amdgcn_global_load_lds((as1v)gb, (as3v)(&lB[buf][(size_t)li * 8]), 16, 0, 0);
    }
  };

  STAGE(0, 0);

  // T4 K-loop: prefetch stays in flight across barriers; vmcnt never drains
  // to 0 mid-loop (R5/R10-verified structure).
  #pragma unroll 1
  for (int kti = 0; kti < 16; kti++) {
    const int cur = kti & 1;
    __builtin_amdgcn_s_barrier();                    // B1: all done reading cur^1
    __builtin_amdgcn_sched_barrier(0);
    if (kti < 15) {
      STAGE(cur ^ 1, (kti + 1) * 64);
      asm volatile("s_waitcnt vmcnt(8)" ::: "memory");   // cur's 8 retired
    } else {
      asm volatile("s_waitcnt vmcnt(0)" ::: "memory");   // final tile
    }
    __builtin_amdgcn_sched_barrier(0);
    __builtin_amdgcn_s_barrier();                    // B2: cur ready for all
    __builtin_amdgcn_sched_barrier(0);
    #pragma unroll
    for (int kk = 0; kk < 2; kk++) {
      const int cs = (((kk << 2) | lq) ^ (lm & 7)) << 3;   // swizzled read col
      short8 af[4], bf[4];
      #pragma unroll
      for (int i = 0; i < 4; i++)
        af[i] = *(const short8*)&lA[cur][(wr + i * 16 + lm) * 64 + cs];
      #pragma unroll
      for (int j = 0; j < 4; j++)
        bf[j] = *(const short8*)&lB[cur][(wc + j * 16 + lm) * 64 + cs];
      #pragma unroll
      for (int i = 0; i < 4; i++)
        #pragma unroll
        for (int j = 0; j < 4; j++)
          acc[i][j] = __builtin_amdgcn_mfma_f32_16x16x32_bf16(af[i], bf[j], acc[i][j], 0, 0, 0);
    }
  }
  // epilogue: bias + bf16 store (scalar u16; L2 write-back merges to full
  // lines — verified R11: bypassing L2 doubles HBM writes)
  #pragma unroll
  for (int i = 0; i < 4; i++) {
    int row0 = by * 128 + wr + i * 16 + lq * 4;
    #pragma unroll
    for (int j = 0; j < 4; j++) {
      int col = bx * 128 + wc + j * 16 + lm;
      float bv = bias[col];
      #pragma unroll
      for (int rg = 0; rg < 4; rg++)
        Cw[(size_t)(row0 + rg) * H3 + col] = f2bf(acc[i][j][rg] + bv);
    }
  }
}

// ---------------------------------------------------------------- final logits GEMM
// T4 counted-vmcnt dbuf (R11, proven transform).
__global__ void __launch_bounds__(256) gemm_final(
    const unsigned short* __restrict__ Abase,   // h bf16 [2048][1024]
    const unsigned short* __restrict__ W,       // h1w_bf [1024][1024]
    float* __restrict__ C)                      // logits [2048][1024]
{
  __shared__ __align__(16) unsigned short lA[2][128 * 64];
  __shared__ __align__(16) unsigned short lB[2][128 * 64];
  const int tid  = threadIdx.x;
  const int lane = tid & 63;
  const int wv   = tid >> 6;
  const int wr   = (wv >> 1) * 64;
  const int wc   = (wv & 1) * 64;
  const int lm   = lane & 15;
  const int lq   = lane >> 4;
  const int bx   = blockIdx.x, by = blockIdx.y;

  f32x4 acc[4][4];
  #pragma unroll
  for (int i = 0; i < 4; i++)
    #pragma unroll
    for (int j = 0; j < 4; j++)
      acc[i][j] = (f32x4){0.f, 0.f, 0.f, 0.f};

  auto STAGE = [&](int buf, int kt) {
    #pragma unroll
    for (int r = 0; r < 4; r++) {
      int li  = r * 256 + tid;
      int row = li >> 3;
      int gc  = (li & 7) ^ (row & 7);
      const unsigned short* ga = Abase + (size_t)(by * 128 + row) * H_ + kt + gc * 8;
      __builtin_amdgcn_global_load_lds((as1v)ga, (as3v)(&lA[buf][(size_t)li * 8]), 16, 0, 0);
      const unsigned short* gb = W + (size_t)(bx * 128 + row) * H_ + kt + gc * 8;
      __builtin_amdgcn_global_load_lds((as1v)gb, (as3v)(&lB[buf][(size_t)li * 8]), 16, 0, 0);
    }
  };

  STAGE(0, 0);

  #pragma unroll 1
  for (int kti = 0; kti < 16; kti++) {
    const int cur = kti & 1;
    __builtin_amdgcn_s_barrier();                    // B1
    __builtin_amdgcn_sched_barrier(0);
    if (kti < 15) {
      STAGE(cur ^ 1, (kti + 1) * 64);
      asm volatile("s_waitcnt vmcnt(8)" ::: "memory");
    } else {
      asm volatile("s_waitcnt vmcnt(0)" ::: "memory");
    }
    __builtin_amdgcn_sched_barrier(0);
    __builtin_amdgcn_s_barrier();                    // B2
    __builtin_amdgcn_sched_barrier(0);
    #pragma unroll
    for (int kk = 0; kk < 2; kk++) {
      const int cs = (((kk << 2) | lq) ^ (lm & 7)) << 3;
      short8 af[4], bf[4];
      #pragma unroll
      for (int i = 0; i < 4; i++)
        af[i] = *(const short8*)&lA[cur][(wr + i * 16 + lm) * 64 + cs];
      #pragma unroll
      for (int j = 0; j < 4; j++)
        bf[j] = *(const short8*)&lB[cur][(wc + j * 16 + lm) * 64 + cs];
      #pragma unroll
      for (int i = 0; i < 4; i++)
        #pragma unroll
        for (int j = 0; j < 4; j++)
          acc[i][j] = __builtin_amdgcn_mfma_f32_16x16x32_bf16(af[i], bf[j], acc[i][j], 0, 0, 0);
    }
  }
  #pragma unroll
  for (int i = 0; i < 4; i++) {
    int row0 = by * 128 + wr + i * 16 + lq * 4;
    #pragma unroll
    for (int j = 0; j < 4; j++) {
      int col = bx * 128 + wc + j * 16 + lm;
      #pragma unroll
      for (int rg = 0; rg < 4; rg++)
        C[(size_t)(row0 + rg) * 1024 + col] = acc[i][j][rg];
    }
  }
}

// ---------------------------------------------------------------- fused GH GEMM + GRU update
// R8 compute form + R13 XCD-aware block decode (verified -82 us).
__global__ void __launch_bounds__(256, 4) step_fused(
    const unsigned short* __restrict__ EW,             // [V,3H] bf16
    const int* __restrict__ uttT, int t,               // token ids, step
    const unsigned short* __restrict__ hin,            // h_{t-1} bf16 [B,H]
    const unsigned short* __restrict__ whh_bf,         // [3H,H] bf16
    const float* __restrict__ bhh,
    float* __restrict__ state,                         // f32 h (in/out)
    unsigned short* __restrict__ hout,                 // h_t bf16 [B,H]
    const unsigned* __restrict__ amask)
{
  __shared__ __align__(16) unsigned short lA[2][64 * 64];       // 16 KB
  __shared__ __align__(16) unsigned short lB[2][3 * 32 * 64];   // 24 KB

  const int tid  = threadIdx.x;
  const int lane = tid & 63;
  const int wv   = tid >> 6;        // 0..3 (row quarter)
  const int lm   = lane & 15;
  const int lq   = lane >> 4;
  // R13 XCD-grouped decode: f = xcd + 8*(bb*4 + hx_low)
  const int f    = blockIdx.x;              // 0..1023
  const int hx   = (f & 7) * 4 + ((f >> 3) & 3);   // 0..31
  const int bb   = f >> 5;                          // 0..31

  // 5 global_load_lds per thread per STAGE — the vmcnt unit below.
  auto STAGE = [&](int buf, int kt) {
    // stage A (h rows): 64x64 bf16 = 2 x 256 x 16B, source block pre-swizzled
    #pragma unroll
    for (int it = 0; it < 2; it++) {
      int li  = it * 256 + tid;
      int row = li >> 3;                  // 0..63
      int gc  = (li & 7) ^ (row & 7);
      const unsigned short* ga = hin + (size_t)(bb * 64 + row) * H_ + kt + gc * 8;
      __builtin_amdgcn_global_load_lds((as1v)ga, (as3v)(&lA[buf][(size_t)li * 8]), 16, 0, 0);
    }
    // stage B (w_hh rows, 3 gates x 32 rows): 3 x 256 x 16B
    #pragma unroll
    for (int gg = 0; gg < 3; gg++) {
      int li  = gg * 256 + tid;
      int g   = li >> 8;                  // == gg
      int row = (li >> 3) & 31;           // 0..31
      int gc  = (li & 7) ^ (row & 7);
      const unsigned short* gb = whh_bf + (size_t)((g << 10) + hx * 32 + row) * H_ + kt + gc * 8;
      __builtin_amdgcn_global_load_lds((as1v)gb, (as3v)(&lB[buf][(size_t)li * 8]), 16, 0, 0);
    }
  };

  // issue first K-tile before the (long-latency) epilogue gather
  STAGE(0, 0);

  // ---- prefetch epilogue operands (latency hides under K-loop; these loads
  // also count in vmcnt — iter 0's vmcnt(5) over-waits them once, harmless)
  int tokr[4];
  #pragma unroll
  for (int rg = 0; rg < 4; rg++)
    tokr[rg] = uttT[t * B_ + bb * 64 + wv * 16 + lq * 4 + rg];

  float hreg[2][4];
  float gir[2][4], giz[2][4], gin[2][4];
  #pragma unroll
  for (int j = 0; j < 2; j++) {
    int col = hx * 32 + j * 16 + lm;
    #pragma unroll
    for (int rg = 0; rg < 4; rg++) {
      int row = bb * 64 + wv * 16 + lq * 4 + rg;
      hreg[j][rg] = state[(size_t)row * H_ + col];
      const unsigned short* ep = EW + (size_t)tokr[rg] * H3 + col;
      gir[j][rg] = bf2f(ep[0]);
      giz[j][rg] = bf2f(ep[H_]);
      gin[j][rg] = bf2f(ep[2 * H_]);
    }
  }

  f32x4 acc[3][2];
  #pragma unroll
  for (int g = 0; g < 3; g++)
    #pragma unroll
    for (int j = 0; j < 2; j++)
      acc[g][j] = (f32x4){0.f, 0.f, 0.f, 0.f};

  // T4 K-loop: prefetch stays in flight across barriers; vmcnt never drains
  // to 0 mid-loop.
  #pragma unroll 1
  for (int kti = 0; kti < 16; kti++) {
    const int cur = kti & 1;
    __builtin_amdgcn_s_barrier();                    // B1
    __builtin_amdgcn_sched_barrier(0);
    if (kti < 15) {
      STAGE(cur ^ 1, (kti + 1) * 64);
      asm volatile("s_waitcnt vmcnt(5)" ::: "memory");   // cur's 5 retired
    } else {
      asm volatile("s_waitcnt vmcnt(0)" ::: "memory");   // final tile
    }
    __builtin_amdgcn_sched_barrier(0);
    __builtin_amdgcn_s_barrier();                    // B2: cur ready for all
    __builtin_amdgcn_sched_barrier(0);
    #pragma unroll
    for (int kk = 0; kk < 2; kk++) {
      const int cs = (((kk << 2) | lq) ^ (lm & 7)) << 3;   // swizzled read col
      short8 af = *(const short8*)&lA[cur][(wv * 16 + lm) * 64 + cs];
      #pragma unroll
      for (int g = 0; g < 3; g++) {
        #pragma unroll
        for (int j = 0; j < 2; j++) {
          short8 bf = *(const short8*)&lB[cur][g * 2048 + (j * 16 + lm) * 64 + cs];
          acc[g][j] = __builtin_amdgcn_mfma_f32_16x16x32_bf16(af, bf, acc[g][j], 0, 0, 0);
        }
      }
    }
  }

  // ---- fused epilogue: bias + gates + GRU update + alive select
  #pragma unroll
  for (int j = 0; j < 2; j++) {
    int col = hx * 32 + j * 16 + lm;
    float bhr = bhh[col];
    float bhz = bhh[H_ + col];
    float bhn = bhh[2 * H_ + col];
    #pragma unroll
    for (int rg = 0; rg < 4; rg++) {
      int row = bb * 64 + wv * 16 + lq * 4 + rg;
      float r = sigmoidf(gir[j][rg] + acc[0][j][rg] + bhr);
      float z = sigmoidf(giz[j][rg] + acc[1][j][rg] + bhz);
      float n = tanhf(gin[j][rg] + r * (acc[2][j][rg] + bhn));
      float h = hreg[j][rg];
      float nh = (1.f - z) * n + z * h;
      float o = ((amask[row] >> t) & 1u) ? nh : h;
      size_t si = (size_t)row * H_ + col;
      state[si] = o;
      hout[si] = f2bf(o);
    }
  }
}

// ---------------------------------------------------------------- softmax head
__global__ void __launch_bounds__(256) softmax_k(const float* __restrict__ logits,
                                                 const float* __restrict__ h1b,
                                                 float* __restrict__ out)
{
  int b = blockIdx.x;
  int tid = threadIdx.x;
  __shared__ float red[8];
  float v[4];
  float lmax = -3.4e38f;
  #pragma unroll
  for (int k = 0; k < 4; k++) {
    int j = tid + k * 256;
    float x = (j < A_) ? (logits[(size_t)b * 1024 + j] + h1b[j]) : -3.4e38f;
    v[k] = x;
    lmax = fmaxf(lmax, x);
  }
  #pragma unroll
  for (int off = 1; off < 64; off <<= 1) lmax = fmaxf(lmax, __shfl_xor(lmax, off, 64));
  if ((tid & 63) == 0) red[tid >> 6] = lmax;
  __syncthreads();
  lmax = fmaxf(fmaxf(red[0], red[1]), fmaxf(red[2], red[3]));
  float s = 0.f;
  #pragma unroll
  for (int k = 0; k < 4; k++) {
    int j = tid + k * 256;
    float e = (j < A_) ? expf(v[k] - lmax) : 0.f;
    v[k] = e; s += e;
  }
  #pragma unroll
  for (int off = 1; off < 64; off <<= 1) s += __shfl_xor(s, off, 64);
  if ((tid & 63) == 0) red[4 + (tid >> 6)] = s;
  __syncthreads();
  s = red[4] + red[5] + red[6] + red[7];
  float inv = 1.f / s;
  #pragma unroll
  for (int k = 0; k < 4; k++) {
    int j = tid + k * 256;
    if (j < A_) out[(size_t)b * A_ + j] = v[k] * inv;
  }
}

// ---------------------------------------------------------------- launch
extern "C" void kernel_launch(void* const* d_in, const int* in_sizes, int n_in,
                              void* d_out, int out_size, void* d_ws, size_t ws_size,
                              hipStream_t stream)
{
  (void)in_sizes; (void)n_in; (void)out_size; (void)ws_size;
  const int*   utt   = (const int*)d_in[0];
  // d_in[1] global_idxes: unused by reference
  const float* emb_w = (const float*)d_in[2];
  const float* w_ih  = (const float*)d_in[3];
  const float* w_hh  = (const float*)d_in[4];
  const float* b_ih  = (const float*)d_in[5];
  const float* b_hh  = (const float*)d_in[6];
  const float* h1_w  = (const float*)d_in[7];
  const float* h1_b  = (const float*)d_in[8];
  float* out = (float*)d_out;

  char* ws = (char*)d_ws;
  size_t off = 0;
  auto alloc = [&](size_t bytes) {
    void* p = ws + off;
    off += (bytes + 255) & ~(size_t)255;
    return p;
  };
  // emb_bf region (65.5 MB) is dead after gemm_ew; overlay the small
  // per-iteration buffers inside it (written only after gemm_ew completes).
  unsigned short* emb_bf = (unsigned short*)alloc((size_t)V_ * H_ * 2);       // 65.5 MB
  unsigned short* wih_bf = (unsigned short*)alloc((size_t)H3 * H_ * 2);       // 6.3 MB
  unsigned short* EW     = (unsigned short*)alloc((size_t)V_ * H3 * 2);       // 196.6 MB
  unsigned short* whh_bf = (unsigned short*)alloc((size_t)H3 * H_ * 2);       // 6.3 MB
  int*            uttT   = (int*)alloc((size_t)B_ * T_ * 4);
  unsigned*       amask  = (unsigned*)alloc((size_t)B_ * 4);

  char* ov = (char*)emb_bf;           // overlay carve
  unsigned short* h1w_bf = (unsigned short*)(ov);                 // 2.1 MB
  float*          state  = (float*)(ov + 2097152);                // 8.4 MB
  unsigned short* hbf0   = (unsigned short*)(ov + 10485760);      // 4.2 MB
  unsigned short* hbf1   = (unsigned short*)(ov + 14680064);      // 4.2 MB
  float*          logits = (float*)(ov + 18874368);               // 8.4 MB  (ends 27.3 MB < 65.5)

  int n4 = V_ * H_ / 4;
  conv_bf16<<<(n4 + 255) / 256, 256, 0, stream>>>(emb_w, emb_bf, n4);
  n4 = H3 * H_ / 4;
  conv_bf16<<<(n4 + 255) / 256, 256, 0, stream>>>(w_ih, wih_bf, n4);
  conv_bf16<<<(n4 + 255) / 256, 256, 0, stream>>>(w_hh, whh_bf, n4);
  prep<<<(B_ + 255) / 256, 256, 0, stream>>>(utt, amask, uttT);

  // R14: 1-D grid, XCD-grouped decode inside the kernel
  gemm_ew<<<6000, 256, 0, stream>>>(emb_bf, wih_bf, b_ih, EW);

  // emb_bf dead from here; overlay region becomes live
  conv_h1w<<<(1024 * 1024) / 256, 256, 0, stream>>>(h1_w, h1w_bf);
  init_state<<<(B_ * H_) / 256, 256, 0, stream>>>(state, hbf0);

  unsigned short* hb[2] = { hbf0, hbf1 };
  for (int t = 0; t < T_; t++) {
    step_fused<<<1024, 256, 0, stream>>>(EW, uttT, t, hb[t & 1], whh_bf, b_hh,
                                         state, hb[(t + 1) & 1], amask);
  }
  dim3 gf(1024 / 128, B_ / 128);      // 8 x 16
  gemm_final<<<gf, 256, 0, stream>>>(hb[0], h1w_bf, logits);
  softmax_k<<<B_, 256, 0, stream>>>(logits, h1_b, out);
}